// Round 6
// baseline (254.517 us; speedup 1.0000x reference)
//
#include <hip/hip_runtime.h>
#include <hip/hip_fp16.h>
#include <stdint.h>

typedef _Float16 f16;
typedef _Float16 f16x8 __attribute__((ext_vector_type(8)));
typedef _Float16 f16x4 __attribute__((ext_vector_type(4)));
typedef float f32x4 __attribute__((ext_vector_type(4)));

#define MFMA16(a, b, c) __builtin_amdgcn_mfma_f32_16x16x32_f16(a, b, c, 0, 0, 0)

constexpr int BB   = 16;
constexpr int NN   = 596;
constexpr int CC   = 768;
constexpr int HH   = 12;
constexpr int DH   = 64;
constexpr int NCLS = 20;
constexpr int BH   = BB * HH;   // 192
constexpr int NP   = 608;       // seq padded to multiple of 32
constexpr int MM   = BB * NN;   // 9536
constexpr int MMP  = 9600;      // M padded to multiple of 128
constexpr int K3C  = 3 * CC;    // 2304
constexpr int NT   = NP / 16;   // 38 col tiles
constexpr int TPW  = 10;        // col tiles per wave-slice
constexpr int QR   = 32;        // q rows per attn block
constexpr int NQT  = NP / QR;   // 19
constexpr int NWG2 = NQT * BH;  // 3648 = 8 * 456

// direct global->LDS DMA, 16B per lane, LDS dest = wave-uniform base + lane*16
__device__ __forceinline__ void gload16(const f16* g, f16* l) {
  __builtin_amdgcn_global_load_lds(
      (const __attribute__((address_space(1))) void*)g,
      (__attribute__((address_space(3))) void*)l, 16, 0, 0);
}

// ---------------------------------------------------------------------------
// K0: fused prep: wqkv^T, wproj^T (fp16), x->fp16 (padded), zero q/k/vT pads.
// Grid: 1728 + 576 + 3600 + 192 = 6096 blocks, 256 threads.
// ---------------------------------------------------------------------------
__global__ __launch_bounds__(256) void prep(
    const float* __restrict__ w_qkv, const float* __restrict__ w_proj,
    const float* __restrict__ x, f16* __restrict__ wqkvT,
    f16* __restrict__ wprojT, f16* __restrict__ x16, f16* __restrict__ q,
    f16* __restrict__ k, f16* __restrict__ vT) {
  __shared__ float t[32][33];
  int b = blockIdx.x;
  if (b < 1728 + 576) {  // transposes
    const float* src = b < 1728 ? w_qkv : w_proj;
    f16* dst = b < 1728 ? wqkvT : wprojT;
    int Ccols = b < 1728 ? K3C : CC;
    int bi = b < 1728 ? b : b - 1728;
    int nbx = Ccols / 32;
    int tile_c = (bi % nbx) * 32, tile_r = (bi / nbx) * 32;
    int tr = threadIdx.x & 31, tg = threadIdx.x >> 5;
#pragma unroll
    for (int i = 0; i < 4; i++)
      t[tg + i * 8][tr] = src[(size_t)(tile_r + tg + i * 8) * Ccols + tile_c + tr];
    __syncthreads();
#pragma unroll
    for (int i = 0; i < 4; i++)
      dst[(size_t)(tile_c + tg + i * 8) * CC + tile_r + tr] =
          (f16)t[tr][tg + i * 8];
    return;
  }
  b -= 1728 + 576;
  if (b < 3600) {  // convert x
    size_t idx = ((size_t)b * 256 + threadIdx.x) * 8;
    f16x8 h;
    if (idx < (size_t)MM * CC) {
      float4 v0 = *reinterpret_cast<const float4*>(&x[idx]);
      float4 v1 = *reinterpret_cast<const float4*>(&x[idx + 4]);
      h[0] = (f16)v0.x; h[1] = (f16)v0.y; h[2] = (f16)v0.z; h[3] = (f16)v0.w;
      h[4] = (f16)v1.x; h[5] = (f16)v1.y; h[6] = (f16)v1.z; h[7] = (f16)v1.w;
    } else {
      h = (f16x8){0, 0, 0, 0, 0, 0, 0, 0};
    }
    *reinterpret_cast<f16x8*>(&x16[idx]) = h;
    return;
  }
  b -= 3600;  // zero pads, b = bh
  int tid = threadIdx.x;
  for (int i = tid; i < 12 * DH; i += 256) {
    int n = NN + (i >> 6), d = i & 63;
    q[((size_t)b * NP + n) * DH + d] = (f16)0.f;
    k[((size_t)b * NP + n) * DH + d] = (f16)0.f;
  }
  for (int i = tid; i < DH * 12; i += 256) {
    int d = i / 12, n = NN + (i % 12);
    vT[((size_t)b * DH + d) * NP + n] = (f16)0.f;
  }
}

// ---------------------------------------------------------------------------
// K1: QKV GEMM, 128x128x64 tiles, global_load_lds staging + XOR swizzle.
// LDS linear [128][64] f16; source chunk (l&7)^(l>>3); read chunk
// (ks*4+lg)^(lr&7)  ->  8 lanes per 4-bank group = LDS throughput floor.
// Grid: (18, 75), block 256.
// ---------------------------------------------------------------------------
__global__ __launch_bounds__(256) void qkv_gemm(
    const f16* __restrict__ x16, const f16* __restrict__ wT,
    const float* __restrict__ bias, f16* __restrict__ q,
    f16* __restrict__ karr, f16* __restrict__ vT) {
  __shared__ f16 As[128 * 64];
  __shared__ f16 Bs[128 * 64];
  int bn = blockIdx.x, bm = blockIdx.y;
  int tid = threadIdx.x;
  int wid = tid >> 6, lane = tid & 63;
  int wm = wid >> 1, wn = wid & 1;
  int lr = lane & 15, lg = lane >> 4;
  int srcChunk = (lane & 7) ^ (lane >> 3);

  const f16* gA = &x16[((size_t)bm * 128 + (lane >> 3)) * CC + srcChunk * 8];
  const f16* gB = &wT[((size_t)bn * 128 + (lane >> 3)) * CC + srcChunk * 8];

  f32x4 acc[4][4] = {};
  for (int k0 = 0; k0 < CC; k0 += 64) {
#pragma unroll
    for (int j = 0; j < 4; j++) {
      int r0 = (wid * 4 + j) * 8;
      gload16(gA + (size_t)r0 * CC + k0, &As[r0 * 64]);
      gload16(gB + (size_t)r0 * CC + k0, &Bs[r0 * 64]);
    }
    __syncthreads();
#pragma unroll
    for (int ks = 0; ks < 2; ks++) {
      f16x8 a[4], b[4];
#pragma unroll
      for (int mt = 0; mt < 4; mt++)
        a[mt] = *reinterpret_cast<const f16x8*>(
            &As[(wm * 64 + mt * 16 + lr) * 64 + ((ks * 4 + lg) ^ (lr & 7)) * 8]);
#pragma unroll
      for (int nt = 0; nt < 4; nt++)
        b[nt] = *reinterpret_cast<const f16x8*>(
            &Bs[(wn * 64 + nt * 16 + lr) * 64 + ((ks * 4 + lg) ^ (lr & 7)) * 8]);
#pragma unroll
      for (int mt = 0; mt < 4; mt++)
#pragma unroll
        for (int nt = 0; nt < 4; nt++)
          acc[mt][nt] = MFMA16(a[mt], b[nt], acc[mt][nt]);
    }
    __syncthreads();
  }

  int which = bn / 6;          // 0=q 1=k 2=v  (768 = 6*128 -> aligned)
  int hbase = (bn % 6) * 128;
#pragma unroll
  for (int mt = 0; mt < 4; mt++)
#pragma unroll
    for (int nt = 0; nt < 4; nt++) {
      int colL = wn * 64 + nt * 16 + lr;
      float bi = bias[bn * 128 + colL];
      int hcol = hbase + colL;
      int h = hcol >> 6, dcol = hcol & 63;
#pragma unroll
      for (int i = 0; i < 4; i++) {
        int m = bm * 128 + wm * 64 + mt * 16 + lg * 4 + i;
        if (m < MM) {
          float val = acc[mt][nt][i] + bi;
          int b = m / NN, n = m - b * NN;
          size_t bh = (size_t)b * HH + h;
          if (which == 0)
            q[(bh * NP + n) * DH + dcol] = (f16)(val * 0.125f);
          else if (which == 1)
            karr[(bh * NP + n) * DH + dcol] = (f16)val;
          else
            vT[(bh * DH + dcol) * NP + n] = (f16)val;
        }
      }
    }
}

// ---------------------------------------------------------------------------
// K2: fused attention, 32 q-rows per block (k/v read once per 32 rows).
// 8 waves: rg = wid>>2 picks 16-row group, ws = wid&3 is slice/d-col group.
// Grid: 3648, block 512.
// ---------------------------------------------------------------------------
__global__ __launch_bounds__(512, 4) void attn_kernel(
    const f16* __restrict__ q, const f16* __restrict__ karr,
    const f16* __restrict__ vT, float* __restrict__ weights,
    f16* __restrict__ ctx) {
  __shared__ f16 P[2][16][616];
  __shared__ float redS[2][4][16];
  __shared__ float invA_lds[2][16];
  __shared__ float invB_lds[2][16];

  int bid = blockIdx.x;
  int wgid = (bid & 7) * (NWG2 / 8) + (bid >> 3);  // bijective XCD swizzle
  int bh = wgid / NQT, qt = wgid - bh * NQT;

  int tid = threadIdx.x, wid = tid >> 6, lane = tid & 63;
  int rg = wid >> 2, ws = wid & 3;
  int lr = lane & 15, lg = lane >> 4;
  int qbase = qt * QR + rg * 16;

  const f16* qrowp = q + ((size_t)bh * NP + qbase + lr) * DH;
  f16x8 a0 = *reinterpret_cast<const f16x8*>(&qrowp[lg * 8]);
  f16x8 a1 = *reinterpret_cast<const f16x8*>(&qrowp[32 + lg * 8]);

  const f16* kb = karr + (size_t)bh * NP * DH;
  float psA[4] = {0.f, 0.f, 0.f, 0.f}, psB[4] = {0.f, 0.f, 0.f, 0.f};
#pragma unroll
  for (int half = 0; half < 2; half++) {
    f16x8 b0[5], b1[5];
#pragma unroll
    for (int j = 0; j < 5; j++) {
      int ct = ws * TPW + half * 5 + j;
      int ctc = ct < NT ? ct : NT - 1;  // clamped (safe) address
      const f16* krp = &kb[(size_t)(ctc * 16 + lr) * DH];
      b0[j] = *reinterpret_cast<const f16x8*>(&krp[lg * 8]);
      b1[j] = *reinterpret_cast<const f16x8*>(&krp[32 + lg * 8]);
    }
#pragma unroll
    for (int j = 0; j < 5; j++) {
      int ct = ws * TPW + half * 5 + j;
      bool live = ct < NT;
      f32x4 acc = {};
      acc = MFMA16(a0, b0[j], acc);
      acc = MFMA16(a1, b1[j], acc);
      int col = ct * 16 + lr;
      bool inA = col < NCLS;
      bool valid = live && (col < NN);
#pragma unroll
      for (int i = 0; i < 4; i++) {
        float e = valid ? __expf(acc[i]) : 0.f;
        if (inA) psA[i] += e; else psB[i] += e;
        if (live) P[rg][lg * 4 + i][col] = (f16)e;
      }
    }
  }
#pragma unroll
  for (int off = 8; off; off >>= 1)
#pragma unroll
    for (int i = 0; i < 4; i++) {
      psA[i] += __shfl_xor(psA[i], off, 16);
      psB[i] += __shfl_xor(psB[i], off, 16);
    }
  if (lr == 0) {
#pragma unroll
    for (int i = 0; i < 4; i++) redS[rg][ws][lg * 4 + i] = psB[i];
    if (ws == 0)  // cls cols live entirely in slice 0
#pragma unroll
      for (int i = 0; i < 4; i++) invA_lds[rg][lg * 4 + i] = 1.0f / psA[i];
  }
  __syncthreads();
  if (ws == 2 && lr == 0)
#pragma unroll
    for (int i = 0; i < 4; i++) {
      int r = lg * 4 + i;
      invB_lds[rg][r] = 1.0f / (redS[rg][0][r] + redS[rg][1][r] +
                                redS[rg][2][r] + redS[rg][3][r]);
    }
  __syncthreads();

  // weights write: static row-per-thread mapping (no int division)
  {
    int row = tid >> 4, sub = tid & 15;  // 32 rows x 16 threads
    int grow = qt * QR + row;
    if (grow < NN) {
      float iA = invA_lds[row >> 4][row & 15];
      float iB = invB_lds[row >> 4][row & 15];
      const f16* prow = &P[row >> 4][row & 15][0];
      float* wrow = weights + ((size_t)bh * NN + grow) * NN;
#pragma unroll
      for (int k2 = 0; k2 < 10; k2++) {
        int f4 = sub + 16 * k2;
        if (f4 < NN / 4) {
          float inv = (f4 < 5) ? iA : iB;
          f16x4 pv = *reinterpret_cast<const f16x4*>(&prow[f4 * 4]);
          float4 o4 = {(float)pv[0] * inv, (float)pv[1] * inv,
                       (float)pv[2] * inv, (float)pv[3] * inv};
          *reinterpret_cast<float4*>(&wrow[f4 * 4]) = o4;
        }
      }
    }
  }

  // PV: wave (rg,ws) -> rows [rg*16,+16), d-cols [ws*16,+16).
  const f16* vrow = vT + (size_t)bh * DH * NP + (size_t)(ws * 16 + lr) * NP;
  f32x4 oA = {}, oB = {};
  {
    f16x8 pa = *reinterpret_cast<const f16x8*>(&P[rg][lr][lg * 8]);
    f16x8 paA = pa, paB = pa;
#pragma unroll
    for (int j = 0; j < 8; j++) {
      if (lg * 8 + j < NCLS) paB[j] = (f16)0.f;
      else paA[j] = (f16)0.f;
    }
    f16x8 bv = *reinterpret_cast<const f16x8*>(&vrow[lg * 8]);
    oA = MFMA16(paA, bv, oA);
    oB = MFMA16(paB, bv, oB);
  }
#pragma unroll
  for (int base = 1; base < 19; base += 6) {
    f16x8 bv[6];
#pragma unroll
    for (int j = 0; j < 6; j++)
      bv[j] = *reinterpret_cast<const f16x8*>(&vrow[(base + j) * 32 + lg * 8]);
#pragma unroll
    for (int j = 0; j < 6; j++) {
      f16x8 pa = *reinterpret_cast<const f16x8*>(
          &P[rg][lr][(base + j) * 32 + lg * 8]);
      oB = MFMA16(pa, bv[j], oB);
    }
  }
  int b = bh / HH, h = bh - b * HH;
#pragma unroll
  for (int i = 0; i < 4; i++) {
    int r = lg * 4 + i;
    int qrow = qbase + r;
    if (qrow < NN) {
      float oval = oA[i] * invA_lds[rg][r] + oB[i] * invB_lds[rg][r];
      ctx[((size_t)b * NN + qrow) * CC + h * DH + ws * 16 + lr] = (f16)oval;
    }
  }
}

// ---------------------------------------------------------------------------
// K3: proj GEMM, 128x128x64 tiles, global_load_lds + XOR swizzle.
// Grid: (6, 75), block 256.
// ---------------------------------------------------------------------------
__global__ __launch_bounds__(256) void proj_gemm(
    const f16* __restrict__ ctx, const f16* __restrict__ wT,
    const float* __restrict__ bias, float* __restrict__ out) {
  __shared__ f16 As[128 * 64];
  __shared__ f16 Bs[128 * 64];
  int bn = blockIdx.x, bm = blockIdx.y;
  int tid = threadIdx.x;
  int wid = tid >> 6, lane = tid & 63;
  int wm = wid >> 1, wn = wid & 1;
  int lr = lane & 15, lg = lane >> 4;
  int srcChunk = (lane & 7) ^ (lane >> 3);

  const f16* gA = &ctx[((size_t)bm * 128 + (lane >> 3)) * CC + srcChunk * 8];
  const f16* gB = &wT[((size_t)bn * 128 + (lane >> 3)) * CC + srcChunk * 8];

  f32x4 acc[4][4] = {};
  for (int k0 = 0; k0 < CC; k0 += 64) {
#pragma unroll
    for (int j = 0; j < 4; j++) {
      int r0 = (wid * 4 + j) * 8;
      gload16(gA + (size_t)r0 * CC + k0, &As[r0 * 64]);
      gload16(gB + (size_t)r0 * CC + k0, &Bs[r0 * 64]);
    }
    __syncthreads();
#pragma unroll
    for (int ks = 0; ks < 2; ks++) {
      f16x8 a[4], b[4];
#pragma unroll
      for (int mt = 0; mt < 4; mt++)
        a[mt] = *reinterpret_cast<const f16x8*>(
            &As[(wm * 64 + mt * 16 + lr) * 64 + ((ks * 4 + lg) ^ (lr & 7)) * 8]);
#pragma unroll
      for (int nt = 0; nt < 4; nt++)
        b[nt] = *reinterpret_cast<const f16x8*>(
            &Bs[(wn * 64 + nt * 16 + lr) * 64 + ((ks * 4 + lg) ^ (lr & 7)) * 8]);
#pragma unroll
      for (int mt = 0; mt < 4; mt++)
#pragma unroll
        for (int nt = 0; nt < 4; nt++)
          acc[mt][nt] = MFMA16(a[mt], b[nt], acc[mt][nt]);
    }
    __syncthreads();
  }
#pragma unroll
  for (int mt = 0; mt < 4; mt++)
#pragma unroll
    for (int nt = 0; nt < 4; nt++) {
      int colL = wn * 64 + nt * 16 + lr;
      float bi = bias[bn * 128 + colL];
#pragma unroll
      for (int i = 0; i < 4; i++) {
        int m = bm * 128 + wm * 64 + mt * 16 + lg * 4 + i;
        if (m < MM)
          out[(size_t)m * CC + bn * 128 + colL] = acc[mt][nt][i] + bi;
      }
    }
}

// ---------------------------------------------------------------------------
extern "C" void kernel_launch(void* const* d_in, const int* in_sizes, int n_in,
                              void* d_out, int out_size, void* d_ws,
                              size_t ws_size, hipStream_t stream) {
  const float* x      = (const float*)d_in[0];
  const float* w_qkv  = (const float*)d_in[1];
  const float* b_qkv  = (const float*)d_in[2];
  const float* w_proj = (const float*)d_in[3];
  const float* b_proj = (const float*)d_in[4];

  float* out     = (float*)d_out;
  float* weights = out + (size_t)MM * CC;

  f16* p      = (f16*)d_ws;
  f16* wqkvT  = p;  p += (size_t)K3C * CC;
  f16* wprojT = p;  p += (size_t)CC * CC;
  f16* x16    = p;  p += (size_t)MMP * CC;
  f16* qb     = p;  p += (size_t)BH * NP * DH;
  f16* kb     = p;  p += (size_t)BH * NP * DH;
  f16* vT     = p;  p += (size_t)BH * DH * NP;
  f16* ctx    = p;  p += (size_t)MMP * CC;

  prep<<<1728 + 576 + 3600 + 192, 256, 0, stream>>>(w_qkv, w_proj, x, wqkvT,
                                                    wprojT, x16, qb, kb, vT);
  qkv_gemm<<<dim3(K3C / 128, MMP / 128), 256, 0, stream>>>(x16, wqkvT, b_qkv,
                                                           qb, kb, vT);
  attn_kernel<<<NWG2, 512, 0, stream>>>(qb, kb, vT, weights, ctx);
  proj_gemm<<<dim3(CC / 128, MMP / 128), 256, 0, stream>>>(ctx, wprojT, b_proj,
                                                           out);
}

// Round 7
// 247.729 us; speedup vs baseline: 1.0274x; 1.0274x over previous
//
#include <hip/hip_runtime.h>
#include <hip/hip_fp16.h>
#include <stdint.h>

typedef _Float16 f16;
typedef _Float16 f16x8 __attribute__((ext_vector_type(8)));
typedef _Float16 f16x4 __attribute__((ext_vector_type(4)));
typedef float f32x4 __attribute__((ext_vector_type(4)));

#define MFMA16(a, b, c) __builtin_amdgcn_mfma_f32_16x16x32_f16(a, b, c, 0, 0, 0)

constexpr int BB   = 16;
constexpr int NN   = 596;
constexpr int CC   = 768;
constexpr int HH   = 12;
constexpr int DH   = 64;
constexpr int NCLS = 20;
constexpr int BH   = BB * HH;   // 192
constexpr int NP   = 608;       // seq padded to multiple of 32
constexpr int MM   = BB * NN;   // 9536
constexpr int MMP  = 9600;      // M padded to multiple of 128
constexpr int K3C  = 3 * CC;    // 2304
constexpr int NT   = NP / 16;   // 38 col tiles
constexpr int TPW  = 10;        // col tiles per wave (4 waves: 10/10/10/8)
constexpr int NWG  = NT * BH;   // 7296 = 8 * 912

// q pre-scale: Dh^-0.5 * log2(e), so attn uses exp2 (raw v_exp_f32)
#define QSCALE 0.18033688011112042f

// direct global->LDS DMA, 16B per lane, LDS dest = wave-uniform base + lane*16
__device__ __forceinline__ void gload16(const f16* g, f16* l) {
  __builtin_amdgcn_global_load_lds(
      (const __attribute__((address_space(1))) void*)g,
      (__attribute__((address_space(3))) void*)l, 16, 0, 0);
}

// ---------------------------------------------------------------------------
// K0: fused prep: wqkv^T, wproj^T (fp16), x->fp16 (padded), zero q/k/vT pads.
// Grid: 1728 + 576 + 3600 + 192 = 6096 blocks, 256 threads.
// ---------------------------------------------------------------------------
__global__ __launch_bounds__(256) void prep(
    const float* __restrict__ w_qkv, const float* __restrict__ w_proj,
    const float* __restrict__ x, f16* __restrict__ wqkvT,
    f16* __restrict__ wprojT, f16* __restrict__ x16, f16* __restrict__ q,
    f16* __restrict__ k, f16* __restrict__ vT) {
  __shared__ float t[32][33];
  int b = blockIdx.x;
  if (b < 1728 + 576) {  // transposes
    const float* src = b < 1728 ? w_qkv : w_proj;
    f16* dst = b < 1728 ? wqkvT : wprojT;
    int Ccols = b < 1728 ? K3C : CC;
    int bi = b < 1728 ? b : b - 1728;
    int nbx = Ccols / 32;
    int tile_c = (bi % nbx) * 32, tile_r = (bi / nbx) * 32;
    int tr = threadIdx.x & 31, tg = threadIdx.x >> 5;
#pragma unroll
    for (int i = 0; i < 4; i++)
      t[tg + i * 8][tr] = src[(size_t)(tile_r + tg + i * 8) * Ccols + tile_c + tr];
    __syncthreads();
#pragma unroll
    for (int i = 0; i < 4; i++)
      dst[(size_t)(tile_c + tg + i * 8) * CC + tile_r + tr] =
          (f16)t[tr][tg + i * 8];
    return;
  }
  b -= 1728 + 576;
  if (b < 3600) {  // convert x
    size_t idx = ((size_t)b * 256 + threadIdx.x) * 8;
    f16x8 h;
    if (idx < (size_t)MM * CC) {
      float4 v0 = *reinterpret_cast<const float4*>(&x[idx]);
      float4 v1 = *reinterpret_cast<const float4*>(&x[idx + 4]);
      h[0] = (f16)v0.x; h[1] = (f16)v0.y; h[2] = (f16)v0.z; h[3] = (f16)v0.w;
      h[4] = (f16)v1.x; h[5] = (f16)v1.y; h[6] = (f16)v1.z; h[7] = (f16)v1.w;
    } else {
      h = (f16x8){0, 0, 0, 0, 0, 0, 0, 0};
    }
    *reinterpret_cast<f16x8*>(&x16[idx]) = h;
    return;
  }
  b -= 3600;  // zero pads, b = bh
  int tid = threadIdx.x;
  for (int i = tid; i < 12 * DH; i += 256) {
    int n = NN + (i >> 6), d = i & 63;
    q[((size_t)b * NP + n) * DH + d] = (f16)0.f;
    k[((size_t)b * NP + n) * DH + d] = (f16)0.f;
  }
  for (int i = tid; i < DH * 12; i += 256) {
    int d = i / 12, n = NN + (i % 12);
    vT[((size_t)b * DH + d) * NP + n] = (f16)0.f;
  }
}

// ---------------------------------------------------------------------------
// K1: QKV GEMM, 128x128x64 tiles, global_load_lds staging + XOR swizzle.
// Grid: (18, 75), block 256.
// ---------------------------------------------------------------------------
__global__ __launch_bounds__(256) void qkv_gemm(
    const f16* __restrict__ x16, const f16* __restrict__ wT,
    const float* __restrict__ bias, f16* __restrict__ q,
    f16* __restrict__ karr, f16* __restrict__ vT) {
  __shared__ f16 As[128 * 64];
  __shared__ f16 Bs[128 * 64];
  int bn = blockIdx.x, bm = blockIdx.y;
  int tid = threadIdx.x;
  int wid = tid >> 6, lane = tid & 63;
  int wm = wid >> 1, wn = wid & 1;
  int lr = lane & 15, lg = lane >> 4;
  int srcChunk = (lane & 7) ^ (lane >> 3);

  const f16* gA = &x16[((size_t)bm * 128 + (lane >> 3)) * CC + srcChunk * 8];
  const f16* gB = &wT[((size_t)bn * 128 + (lane >> 3)) * CC + srcChunk * 8];

  f32x4 acc[4][4] = {};
  for (int k0 = 0; k0 < CC; k0 += 64) {
#pragma unroll
    for (int j = 0; j < 4; j++) {
      int r0 = (wid * 4 + j) * 8;
      gload16(gA + (size_t)r0 * CC + k0, &As[r0 * 64]);
      gload16(gB + (size_t)r0 * CC + k0, &Bs[r0 * 64]);
    }
    __syncthreads();
#pragma unroll
    for (int ks = 0; ks < 2; ks++) {
      f16x8 a[4], b[4];
#pragma unroll
      for (int mt = 0; mt < 4; mt++)
        a[mt] = *reinterpret_cast<const f16x8*>(
            &As[(wm * 64 + mt * 16 + lr) * 64 + ((ks * 4 + lg) ^ (lr & 7)) * 8]);
#pragma unroll
      for (int nt = 0; nt < 4; nt++)
        b[nt] = *reinterpret_cast<const f16x8*>(
            &Bs[(wn * 64 + nt * 16 + lr) * 64 + ((ks * 4 + lg) ^ (lr & 7)) * 8]);
#pragma unroll
      for (int mt = 0; mt < 4; mt++)
#pragma unroll
        for (int nt = 0; nt < 4; nt++)
          acc[mt][nt] = MFMA16(a[mt], b[nt], acc[mt][nt]);
    }
    __syncthreads();
  }

  int which = bn / 6;          // 0=q 1=k 2=v  (768 = 6*128 -> aligned)
  int hbase = (bn % 6) * 128;
#pragma unroll
  for (int mt = 0; mt < 4; mt++)
#pragma unroll
    for (int nt = 0; nt < 4; nt++) {
      int colL = wn * 64 + nt * 16 + lr;
      float bi = bias[bn * 128 + colL];
      int hcol = hbase + colL;
      int h = hcol >> 6, dcol = hcol & 63;
#pragma unroll
      for (int i = 0; i < 4; i++) {
        int m = bm * 128 + wm * 64 + mt * 16 + lg * 4 + i;
        if (m < MM) {
          float val = acc[mt][nt][i] + bi;
          int b = m / NN, n = m - b * NN;
          size_t bh = (size_t)b * HH + h;
          if (which == 0)
            q[(bh * NP + n) * DH + dcol] = (f16)(val * QSCALE);
          else if (which == 1)
            karr[(bh * NP + n) * DH + dcol] = (f16)val;
          else
            vT[(bh * DH + dcol) * NP + n] = (f16)val;
        }
      }
    }
}

// ---------------------------------------------------------------------------
// K2: fused attention (R5 structure: 4 waves, 16 q-rows/block).
// exp2-domain scores (scale folded into q), unnormalized P in LDS,
// deferred normalization, coalesced weights write (static mapping).
// Grid: 7296, block 256.
// ---------------------------------------------------------------------------
__global__ __launch_bounds__(256) void attn_kernel(
    const f16* __restrict__ q, const f16* __restrict__ karr,
    const f16* __restrict__ vT, float* __restrict__ weights,
    f16* __restrict__ ctx) {
  __shared__ f16 P[16][616];
  __shared__ float redS[4][16];
  __shared__ float invA_lds[16];
  __shared__ float invB_lds[16];

  int bid = blockIdx.x;
  int wgid = (bid & 7) * (NWG / 8) + (bid >> 3);  // bijective XCD swizzle
  int bh = wgid / NT, qt = wgid - bh * NT;

  int tid = threadIdx.x, wid = tid >> 6, lane = tid & 63;
  int lr = lane & 15, lg = lane >> 4;
  int qbase = qt * 16;

  const f16* qrowp = q + ((size_t)bh * NP + qbase + lr) * DH;
  f16x8 a0 = *reinterpret_cast<const f16x8*>(&qrowp[lg * 8]);
  f16x8 a1 = *reinterpret_cast<const f16x8*>(&qrowp[32 + lg * 8]);

  const f16* kb = karr + (size_t)bh * NP * DH;
  float psA[4] = {0.f, 0.f, 0.f, 0.f}, psB[4] = {0.f, 0.f, 0.f, 0.f};
#pragma unroll
  for (int half = 0; half < 2; half++) {
    f16x8 b0[5], b1[5];
#pragma unroll
    for (int j = 0; j < 5; j++) {
      int ct = wid * TPW + half * 5 + j;
      int ctc = ct < NT ? ct : NT - 1;  // clamped (safe) address
      const f16* krp = &kb[(size_t)(ctc * 16 + lr) * DH];
      b0[j] = *reinterpret_cast<const f16x8*>(&krp[lg * 8]);
      b1[j] = *reinterpret_cast<const f16x8*>(&krp[32 + lg * 8]);
    }
#pragma unroll
    for (int j = 0; j < 5; j++) {
      int ct = wid * TPW + half * 5 + j;
      bool live = ct < NT;
      f32x4 acc = {};
      acc = MFMA16(a0, b0[j], acc);
      acc = MFMA16(a1, b1[j], acc);
      int col = ct * 16 + lr;
      bool inA = col < NCLS;
      bool valid = live && (col < NN);
#pragma unroll
      for (int i = 0; i < 4; i++) {
        float e = valid ? __builtin_amdgcn_exp2f(acc[i]) : 0.f;
        if (inA) psA[i] += e; else psB[i] += e;
        if (live) P[lg * 4 + i][col] = (f16)e;
      }
    }
  }
#pragma unroll
  for (int off = 8; off; off >>= 1)
#pragma unroll
    for (int i = 0; i < 4; i++) {
      psA[i] += __shfl_xor(psA[i], off, 16);
      psB[i] += __shfl_xor(psB[i], off, 16);
    }
  if (lr == 0) {
#pragma unroll
    for (int i = 0; i < 4; i++) redS[wid][lg * 4 + i] = psB[i];
    if (wid == 0)  // cls cols live entirely in wave 0
#pragma unroll
      for (int i = 0; i < 4; i++) invA_lds[lg * 4 + i] = 1.0f / psA[i];
  }
  __syncthreads();
  if (wid == 2 && lr == 0)
#pragma unroll
    for (int i = 0; i < 4; i++) {
      int r = lg * 4 + i;
      invB_lds[r] =
          1.0f / (redS[0][r] + redS[1][r] + redS[2][r] + redS[3][r]);
    }
  __syncthreads();

  // weights write: static row-per-thread mapping (16 rows x 16 threads)
  {
    int row = tid >> 4, sub = tid & 15;
    int grow = qbase + row;
    if (grow < NN) {
      float iA = invA_lds[row];
      float iB = invB_lds[row];
      const f16* prow = &P[row][0];
      float* wrow = weights + ((size_t)bh * NN + grow) * NN;
#pragma unroll
      for (int k2 = 0; k2 < 10; k2++) {
        int f4 = sub + 16 * k2;
        if (f4 < NN / 4) {
          float inv = (f4 < 5) ? iA : iB;
          f16x4 pv = *reinterpret_cast<const f16x4*>(&prow[f4 * 4]);
          float4 o4 = {(float)pv[0] * inv, (float)pv[1] * inv,
                       (float)pv[2] * inv, (float)pv[3] * inv};
          *reinterpret_cast<float4*>(&wrow[f4 * 4]) = o4;
        }
      }
    }
  }

  // PV: wave w owns d-cols [16w,16w+16); cls part in oA, patch part in oB.
  const f16* vrow = vT + (size_t)bh * DH * NP + (size_t)(wid * 16 + lr) * NP;
  f32x4 oA = {}, oB = {};
  {
    f16x8 pa = *reinterpret_cast<const f16x8*>(&P[lr][lg * 8]);
    f16x8 paA = pa, paB = pa;
#pragma unroll
    for (int j = 0; j < 8; j++) {
      if (lg * 8 + j < NCLS) paB[j] = (f16)0.f;
      else paA[j] = (f16)0.f;
    }
    f16x8 bv = *reinterpret_cast<const f16x8*>(&vrow[lg * 8]);
    oA = MFMA16(paA, bv, oA);
    oB = MFMA16(paB, bv, oB);
  }
#pragma unroll
  for (int base = 1; base < 19; base += 6) {
    f16x8 bv[6];
#pragma unroll
    for (int j = 0; j < 6; j++)
      bv[j] = *reinterpret_cast<const f16x8*>(&vrow[(base + j) * 32 + lg * 8]);
#pragma unroll
    for (int j = 0; j < 6; j++) {
      f16x8 pa =
          *reinterpret_cast<const f16x8*>(&P[lr][(base + j) * 32 + lg * 8]);
      oB = MFMA16(pa, bv[j], oB);
    }
  }
  int b = bh / HH, h = bh - b * HH;
#pragma unroll
  for (int i = 0; i < 4; i++) {
    int r = lg * 4 + i;
    int qrow = qbase + r;
    if (qrow < NN) {
      float oval = oA[i] * invA_lds[r] + oB[i] * invB_lds[r];
      ctx[((size_t)b * NN + qrow) * CC + h * DH + wid * 16 + lr] = (f16)oval;
    }
  }
}

// ---------------------------------------------------------------------------
// K3: proj GEMM, 128x128x64 tiles, global_load_lds + XOR swizzle.
// Grid: (6, 75), block 256.
// ---------------------------------------------------------------------------
__global__ __launch_bounds__(256) void proj_gemm(
    const f16* __restrict__ ctx, const f16* __restrict__ wT,
    const float* __restrict__ bias, float* __restrict__ out) {
  __shared__ f16 As[128 * 64];
  __shared__ f16 Bs[128 * 64];
  int bn = blockIdx.x, bm = blockIdx.y;
  int tid = threadIdx.x;
  int wid = tid >> 6, lane = tid & 63;
  int wm = wid >> 1, wn = wid & 1;
  int lr = lane & 15, lg = lane >> 4;
  int srcChunk = (lane & 7) ^ (lane >> 3);

  const f16* gA = &ctx[((size_t)bm * 128 + (lane >> 3)) * CC + srcChunk * 8];
  const f16* gB = &wT[((size_t)bn * 128 + (lane >> 3)) * CC + srcChunk * 8];

  f32x4 acc[4][4] = {};
  for (int k0 = 0; k0 < CC; k0 += 64) {
#pragma unroll
    for (int j = 0; j < 4; j++) {
      int r0 = (wid * 4 + j) * 8;
      gload16(gA + (size_t)r0 * CC + k0, &As[r0 * 64]);
      gload16(gB + (size_t)r0 * CC + k0, &Bs[r0 * 64]);
    }
    __syncthreads();
#pragma unroll
    for (int ks = 0; ks < 2; ks++) {
      f16x8 a[4], b[4];
#pragma unroll
      for (int mt = 0; mt < 4; mt++)
        a[mt] = *reinterpret_cast<const f16x8*>(
            &As[(wm * 64 + mt * 16 + lr) * 64 + ((ks * 4 + lg) ^ (lr & 7)) * 8]);
#pragma unroll
      for (int nt = 0; nt < 4; nt++)
        b[nt] = *reinterpret_cast<const f16x8*>(
            &Bs[(wn * 64 + nt * 16 + lr) * 64 + ((ks * 4 + lg) ^ (lr & 7)) * 8]);
#pragma unroll
      for (int mt = 0; mt < 4; mt++)
#pragma unroll
        for (int nt = 0; nt < 4; nt++)
          acc[mt][nt] = MFMA16(a[mt], b[nt], acc[mt][nt]);
    }
    __syncthreads();
  }
#pragma unroll
  for (int mt = 0; mt < 4; mt++)
#pragma unroll
    for (int nt = 0; nt < 4; nt++) {
      int colL = wn * 64 + nt * 16 + lr;
      float bi = bias[bn * 128 + colL];
#pragma unroll
      for (int i = 0; i < 4; i++) {
        int m = bm * 128 + wm * 64 + mt * 16 + lg * 4 + i;
        if (m < MM)
          out[(size_t)m * CC + bn * 128 + colL] = acc[mt][nt][i] + bi;
      }
    }
}

// ---------------------------------------------------------------------------
extern "C" void kernel_launch(void* const* d_in, const int* in_sizes, int n_in,
                              void* d_out, int out_size, void* d_ws,
                              size_t ws_size, hipStream_t stream) {
  const float* x      = (const float*)d_in[0];
  const float* w_qkv  = (const float*)d_in[1];
  const float* b_qkv  = (const float*)d_in[2];
  const float* w_proj = (const float*)d_in[3];
  const float* b_proj = (const float*)d_in[4];

  float* out     = (float*)d_out;
  float* weights = out + (size_t)MM * CC;

  f16* p      = (f16*)d_ws;
  f16* wqkvT  = p;  p += (size_t)K3C * CC;
  f16* wprojT = p;  p += (size_t)CC * CC;
  f16* x16    = p;  p += (size_t)MMP * CC;
  f16* qb     = p;  p += (size_t)BH * NP * DH;
  f16* kb     = p;  p += (size_t)BH * NP * DH;
  f16* vT     = p;  p += (size_t)BH * DH * NP;
  f16* ctx    = p;  p += (size_t)MMP * CC;

  prep<<<1728 + 576 + 3600 + 192, 256, 0, stream>>>(w_qkv, w_proj, x, wqkvT,
                                                    wprojT, x16, qb, kb, vT);
  qkv_gemm<<<dim3(K3C / 128, MMP / 128), 256, 0, stream>>>(x16, wqkvT, b_qkv,
                                                           qb, kb, vT);
  attn_kernel<<<NWG, 256, 0, stream>>>(qb, kb, vT, weights, ctx);
  proj_gemm<<<dim3(CC / 128, MMP / 128), 256, 0, stream>>>(ctx, wprojT, b_proj,
                                                           out);
}

// Round 8
// 247.120 us; speedup vs baseline: 1.0299x; 1.0025x over previous
//
#include <hip/hip_runtime.h>
#include <hip/hip_fp16.h>
#include <stdint.h>

typedef _Float16 f16;
typedef _Float16 f16x8 __attribute__((ext_vector_type(8)));
typedef _Float16 f16x4 __attribute__((ext_vector_type(4)));
typedef float f32x4 __attribute__((ext_vector_type(4)));

#define MFMA16(a, b, c) __builtin_amdgcn_mfma_f32_16x16x32_f16(a, b, c, 0, 0, 0)

constexpr int BB   = 16;
constexpr int NN   = 596;
constexpr int CC   = 768;
constexpr int HH   = 12;
constexpr int DH   = 64;
constexpr int NCLS = 20;
constexpr int BH   = BB * HH;   // 192
constexpr int NP   = 608;       // seq padded to multiple of 32
constexpr int MM   = BB * NN;   // 9536
constexpr int MMP  = 9600;      // M padded to multiple of 128
constexpr int K3C  = 3 * CC;    // 2304
constexpr int NT   = NP / 16;   // 38 col tiles
constexpr int TPW  = 10;        // col tiles per wave (4 waves: 10/10/10/8)
constexpr int NWG  = NT * BH;   // 7296 = 8 * 912

// q pre-scale: Dh^-0.5 * log2(e), so attn uses exp2 (raw v_exp_f32)
#define QSCALE 0.18033688011112042f

// direct global->LDS DMA, 16B per lane, LDS dest = wave-uniform base + lane*16
__device__ __forceinline__ void gload16(const f16* g, f16* l) {
  __builtin_amdgcn_global_load_lds(
      (const __attribute__((address_space(1))) void*)g,
      (__attribute__((address_space(3))) void*)l, 16, 0, 0);
}

// ---------------------------------------------------------------------------
// K0: fused prep: wqkv^T, wproj^T (fp16), x->fp16 (padded), zero q/k/vT pads.
// Grid: 1728 + 576 + 3600 + 192 = 6096 blocks, 256 threads.
// ---------------------------------------------------------------------------
__global__ __launch_bounds__(256) void prep(
    const float* __restrict__ w_qkv, const float* __restrict__ w_proj,
    const float* __restrict__ x, f16* __restrict__ wqkvT,
    f16* __restrict__ wprojT, f16* __restrict__ x16, f16* __restrict__ q,
    f16* __restrict__ k, f16* __restrict__ vT) {
  __shared__ float t[32][33];
  int b = blockIdx.x;
  if (b < 1728 + 576) {  // transposes
    const float* src = b < 1728 ? w_qkv : w_proj;
    f16* dst = b < 1728 ? wqkvT : wprojT;
    int Ccols = b < 1728 ? K3C : CC;
    int bi = b < 1728 ? b : b - 1728;
    int nbx = Ccols / 32;
    int tile_c = (bi % nbx) * 32, tile_r = (bi / nbx) * 32;
    int tr = threadIdx.x & 31, tg = threadIdx.x >> 5;
#pragma unroll
    for (int i = 0; i < 4; i++)
      t[tg + i * 8][tr] = src[(size_t)(tile_r + tg + i * 8) * Ccols + tile_c + tr];
    __syncthreads();
#pragma unroll
    for (int i = 0; i < 4; i++)
      dst[(size_t)(tile_c + tg + i * 8) * CC + tile_r + tr] =
          (f16)t[tr][tg + i * 8];
    return;
  }
  b -= 1728 + 576;
  if (b < 3600) {  // convert x
    size_t idx = ((size_t)b * 256 + threadIdx.x) * 8;
    f16x8 h;
    if (idx < (size_t)MM * CC) {
      float4 v0 = *reinterpret_cast<const float4*>(&x[idx]);
      float4 v1 = *reinterpret_cast<const float4*>(&x[idx + 4]);
      h[0] = (f16)v0.x; h[1] = (f16)v0.y; h[2] = (f16)v0.z; h[3] = (f16)v0.w;
      h[4] = (f16)v1.x; h[5] = (f16)v1.y; h[6] = (f16)v1.z; h[7] = (f16)v1.w;
    } else {
      h = (f16x8){0, 0, 0, 0, 0, 0, 0, 0};
    }
    *reinterpret_cast<f16x8*>(&x16[idx]) = h;
    return;
  }
  b -= 3600;  // zero pads, b = bh
  int tid = threadIdx.x;
  for (int i = tid; i < 12 * DH; i += 256) {
    int n = NN + (i >> 6), d = i & 63;
    q[((size_t)b * NP + n) * DH + d] = (f16)0.f;
    k[((size_t)b * NP + n) * DH + d] = (f16)0.f;
  }
  for (int i = tid; i < DH * 12; i += 256) {
    int d = i / 12, n = NN + (i % 12);
    vT[((size_t)b * DH + d) * NP + n] = (f16)0.f;
  }
}

// ---------------------------------------------------------------------------
// K1: QKV GEMM, 128x128x64 tiles, global_load_lds staging + XOR swizzle.
// Grid: (18, 75), block 256.
// ---------------------------------------------------------------------------
__global__ __launch_bounds__(256) void qkv_gemm(
    const f16* __restrict__ x16, const f16* __restrict__ wT,
    const float* __restrict__ bias, f16* __restrict__ q,
    f16* __restrict__ karr, f16* __restrict__ vT) {
  __shared__ f16 As[128 * 64];
  __shared__ f16 Bs[128 * 64];
  int bn = blockIdx.x, bm = blockIdx.y;
  int tid = threadIdx.x;
  int wid = tid >> 6, lane = tid & 63;
  int wm = wid >> 1, wn = wid & 1;
  int lr = lane & 15, lg = lane >> 4;
  int srcChunk = (lane & 7) ^ (lane >> 3);

  const f16* gA = &x16[((size_t)bm * 128 + (lane >> 3)) * CC + srcChunk * 8];
  const f16* gB = &wT[((size_t)bn * 128 + (lane >> 3)) * CC + srcChunk * 8];

  f32x4 acc[4][4] = {};
  for (int k0 = 0; k0 < CC; k0 += 64) {
#pragma unroll
    for (int j = 0; j < 4; j++) {
      int r0 = (wid * 4 + j) * 8;
      gload16(gA + (size_t)r0 * CC + k0, &As[r0 * 64]);
      gload16(gB + (size_t)r0 * CC + k0, &Bs[r0 * 64]);
    }
    __syncthreads();
#pragma unroll
    for (int ks = 0; ks < 2; ks++) {
      f16x8 a[4], b[4];
#pragma unroll
      for (int mt = 0; mt < 4; mt++)
        a[mt] = *reinterpret_cast<const f16x8*>(
            &As[(wm * 64 + mt * 16 + lr) * 64 + ((ks * 4 + lg) ^ (lr & 7)) * 8]);
#pragma unroll
      for (int nt = 0; nt < 4; nt++)
        b[nt] = *reinterpret_cast<const f16x8*>(
            &Bs[(wn * 64 + nt * 16 + lr) * 64 + ((ks * 4 + lg) ^ (lr & 7)) * 8]);
#pragma unroll
      for (int mt = 0; mt < 4; mt++)
#pragma unroll
        for (int nt = 0; nt < 4; nt++)
          acc[mt][nt] = MFMA16(a[mt], b[nt], acc[mt][nt]);
    }
    __syncthreads();
  }

  int which = bn / 6;          // 0=q 1=k 2=v  (768 = 6*128 -> aligned)
  int hbase = (bn % 6) * 128;
#pragma unroll
  for (int mt = 0; mt < 4; mt++)
#pragma unroll
    for (int nt = 0; nt < 4; nt++) {
      int colL = wn * 64 + nt * 16 + lr;
      float bi = bias[bn * 128 + colL];
      int hcol = hbase + colL;
      int h = hcol >> 6, dcol = hcol & 63;
#pragma unroll
      for (int i = 0; i < 4; i++) {
        int m = bm * 128 + wm * 64 + mt * 16 + lg * 4 + i;
        if (m < MM) {
          float val = acc[mt][nt][i] + bi;
          int b = m / NN, n = m - b * NN;
          size_t bh = (size_t)b * HH + h;
          if (which == 0)
            q[(bh * NP + n) * DH + dcol] = (f16)(val * QSCALE);
          else if (which == 1)
            karr[(bh * NP + n) * DH + dcol] = (f16)val;
          else
            vT[(bh * DH + dcol) * NP + n] = (f16)val;
        }
      }
    }
}

// ---------------------------------------------------------------------------
// K2: fused attention, swapped-operand MFMA layout.
// S^T = mfma(K,Q): each lane holds 4 consecutive k-cols of ONE q-row (lr) ->
// packed ds_write_b64 P stores, per-lane row sums (2 shfl_xor), per-lane inv.
// PV = mfma(V,P): D[d][q] -> 8B ctx stores. V batch-1 loads issued before the
// weights-write phase to hide HBM latency under it.
// Grid: 7296, block 256 (4 waves).
// ---------------------------------------------------------------------------
__global__ __launch_bounds__(256) void attn_kernel(
    const f16* __restrict__ q, const f16* __restrict__ karr,
    const f16* __restrict__ vT, float* __restrict__ weights,
    f16* __restrict__ ctx) {
  __shared__ f16 P[16][616];  // unnormalized exp2(scores), [q-row][k-col]
  __shared__ float redS[4][16];
  __shared__ float invA_lds[16];
  __shared__ float invB_lds[16];

  int bid = blockIdx.x;
  int wgid = (bid & 7) * (NWG / 8) + (bid >> 3);  // bijective XCD swizzle
  int bh = wgid / NT, qt = wgid - bh * NT;

  int tid = threadIdx.x, wid = tid >> 6, lane = tid & 63;
  int lr = lane & 15, lg = lane >> 4;
  int qbase = qt * 16;

  const f16* qrowp = q + ((size_t)bh * NP + qbase + lr) * DH;
  f16x8 a0 = *reinterpret_cast<const f16x8*>(&qrowp[lg * 8]);
  f16x8 a1 = *reinterpret_cast<const f16x8*>(&qrowp[32 + lg * 8]);

  const f16* kb = karr + (size_t)bh * NP * DH;
  float psA = 0.f, psB = 0.f;  // per-lane partials for q-row lr
#pragma unroll
  for (int half = 0; half < 2; half++) {
    f16x8 b0[5], b1[5];
#pragma unroll
    for (int j = 0; j < 5; j++) {
      int ct = wid * TPW + half * 5 + j;
      int ctc = ct < NT ? ct : NT - 1;  // clamped (safe) address
      const f16* krp = &kb[(size_t)(ctc * 16 + lr) * DH];
      b0[j] = *reinterpret_cast<const f16x8*>(&krp[lg * 8]);
      b1[j] = *reinterpret_cast<const f16x8*>(&krp[32 + lg * 8]);
    }
#pragma unroll
    for (int j = 0; j < 5; j++) {
      int ct = wid * TPW + half * 5 + j;
      bool live = ct < NT;
      f32x4 acc = {};
      acc = MFMA16(b0[j], a0, acc);   // S^T: row = k-col, col = q-row
      acc = MFMA16(b1[j], a1, acc);
      f16x4 pk;
#pragma unroll
      for (int i = 0; i < 4; i++) {
        int col = ct * 16 + lg * 4 + i;   // k column
        bool inA = col < NCLS;
        bool valid = live && (col < NN);
        float e = valid ? __builtin_amdgcn_exp2f(acc[i]) : 0.f;
        if (inA) psA += e; else psB += e;
        pk[i] = (f16)e;
      }
      if (live)
        *reinterpret_cast<f16x4*>(&P[lr][ct * 16 + lg * 4]) = pk;
    }
  }
  // reduce across the 4 lanes sharing q-row lr (lanes lr, lr+16, lr+32, lr+48)
  psA += __shfl_xor(psA, 16);
  psA += __shfl_xor(psA, 32);
  psB += __shfl_xor(psB, 16);
  psB += __shfl_xor(psB, 32);
  if (lane < 16) {
    redS[wid][lr] = psB;
    if (wid == 0) invA_lds[lr] = 1.0f / psA;  // cls cols live in wave 0
  }
  __syncthreads();
  if (wid == 2 && lane < 16)
    invB_lds[lr] =
        1.0f / (redS[0][lr] + redS[1][lr] + redS[2][lr] + redS[3][lr]);
  __syncthreads();

  // issue PV batch-1 V loads now; latency hides under the weights write
  const f16* vrow = vT + (size_t)bh * DH * NP + (size_t)(wid * 16 + lr) * NP;
  f16x8 bv0[6];
#pragma unroll
  for (int j = 0; j < 6; j++)
    bv0[j] = *reinterpret_cast<const f16x8*>(&vrow[j * 32 + lg * 8]);

  // weights write: static row-per-thread mapping (16 rows x 16 threads)
  {
    int row = tid >> 4, sub = tid & 15;
    int grow = qbase + row;
    if (grow < NN) {
      float iA = invA_lds[row];
      float iB = invB_lds[row];
      const f16* prow = &P[row][0];
      float* wrow = weights + ((size_t)bh * NN + grow) * NN;
#pragma unroll
      for (int k2 = 0; k2 < 10; k2++) {
        int f4 = sub + 16 * k2;
        if (f4 < NN / 4) {
          float inv = (f4 < 5) ? iA : iB;
          f16x4 pv = *reinterpret_cast<const f16x4*>(&prow[f4 * 4]);
          float4 o4 = {(float)pv[0] * inv, (float)pv[1] * inv,
                       (float)pv[2] * inv, (float)pv[3] * inv};
          *reinterpret_cast<float4*>(&wrow[f4 * 4]) = o4;
        }
      }
    }
  }

  // PV (swapped): D[d][q]; cls part in oA, patch part in oB.
  f32x4 oA = {}, oB = {};
  {
    f16x8 pa = *reinterpret_cast<const f16x8*>(&P[lr][lg * 8]);
    f16x8 paA = pa, paB = pa;
#pragma unroll
    for (int j = 0; j < 8; j++) {
      if (lg * 8 + j < NCLS) paB[j] = (f16)0.f;
      else paA[j] = (f16)0.f;
    }
    oA = MFMA16(bv0[0], paA, oA);
    oB = MFMA16(bv0[0], paB, oB);
  }
#pragma unroll
  for (int j = 1; j < 6; j++) {
    f16x8 pa = *reinterpret_cast<const f16x8*>(&P[lr][j * 32 + lg * 8]);
    oB = MFMA16(bv0[j], pa, oB);
  }
  {
    f16x8 bv[7];
#pragma unroll
    for (int j = 0; j < 7; j++)
      bv[j] = *reinterpret_cast<const f16x8*>(&vrow[(6 + j) * 32 + lg * 8]);
#pragma unroll
    for (int j = 0; j < 7; j++) {
      f16x8 pa = *reinterpret_cast<const f16x8*>(&P[lr][(6 + j) * 32 + lg * 8]);
      oB = MFMA16(bv[j], pa, oB);
    }
  }
  {
    f16x8 bv[6];
#pragma unroll
    for (int j = 0; j < 6; j++)
      bv[j] = *reinterpret_cast<const f16x8*>(&vrow[(13 + j) * 32 + lg * 8]);
#pragma unroll
    for (int j = 0; j < 6; j++) {
      f16x8 pa = *reinterpret_cast<const f16x8*>(&P[lr][(13 + j) * 32 + lg * 8]);
      oB = MFMA16(bv[j], pa, oB);
    }
  }

  // epilogue: lane holds D[d = wid*16 + lg*4 + i][q = lr] -> one 8B store
  int qrow = qbase + lr;
  if (qrow < NN) {
    float iA = invA_lds[lr], iB = invB_lds[lr];
    int b = bh / HH, h = bh - b * HH;
    f16x4 o4;
#pragma unroll
    for (int i = 0; i < 4; i++) o4[i] = (f16)(oA[i] * iA + oB[i] * iB);
    *reinterpret_cast<f16x4*>(
        &ctx[((size_t)b * NN + qrow) * CC + h * DH + wid * 16 + lg * 4]) = o4;
  }
}

// ---------------------------------------------------------------------------
// K3: proj GEMM, 128x128x64 tiles, global_load_lds + XOR swizzle.
// Grid: (6, 75), block 256.
// ---------------------------------------------------------------------------
__global__ __launch_bounds__(256) void proj_gemm(
    const f16* __restrict__ ctx, const f16* __restrict__ wT,
    const float* __restrict__ bias, float* __restrict__ out) {
  __shared__ f16 As[128 * 64];
  __shared__ f16 Bs[128 * 64];
  int bn = blockIdx.x, bm = blockIdx.y;
  int tid = threadIdx.x;
  int wid = tid >> 6, lane = tid & 63;
  int wm = wid >> 1, wn = wid & 1;
  int lr = lane & 15, lg = lane >> 4;
  int srcChunk = (lane & 7) ^ (lane >> 3);

  const f16* gA = &ctx[((size_t)bm * 128 + (lane >> 3)) * CC + srcChunk * 8];
  const f16* gB = &wT[((size_t)bn * 128 + (lane >> 3)) * CC + srcChunk * 8];

  f32x4 acc[4][4] = {};
  for (int k0 = 0; k0 < CC; k0 += 64) {
#pragma unroll
    for (int j = 0; j < 4; j++) {
      int r0 = (wid * 4 + j) * 8;
      gload16(gA + (size_t)r0 * CC + k0, &As[r0 * 64]);
      gload16(gB + (size_t)r0 * CC + k0, &Bs[r0 * 64]);
    }
    __syncthreads();
#pragma unroll
    for (int ks = 0; ks < 2; ks++) {
      f16x8 a[4], b[4];
#pragma unroll
      for (int mt = 0; mt < 4; mt++)
        a[mt] = *reinterpret_cast<const f16x8*>(
            &As[(wm * 64 + mt * 16 + lr) * 64 + ((ks * 4 + lg) ^ (lr & 7)) * 8]);
#pragma unroll
      for (int nt = 0; nt < 4; nt++)
        b[nt] = *reinterpret_cast<const f16x8*>(
            &Bs[(wn * 64 + nt * 16 + lr) * 64 + ((ks * 4 + lg) ^ (lr & 7)) * 8]);
#pragma unroll
      for (int mt = 0; mt < 4; mt++)
#pragma unroll
        for (int nt = 0; nt < 4; nt++)
          acc[mt][nt] = MFMA16(a[mt], b[nt], acc[mt][nt]);
    }
    __syncthreads();
  }
#pragma unroll
  for (int mt = 0; mt < 4; mt++)
#pragma unroll
    for (int nt = 0; nt < 4; nt++) {
      int colL = wn * 64 + nt * 16 + lr;
      float bi = bias[bn * 128 + colL];
#pragma unroll
      for (int i = 0; i < 4; i++) {
        int m = bm * 128 + wm * 64 + mt * 16 + lg * 4 + i;
        if (m < MM)
          out[(size_t)m * CC + bn * 128 + colL] = acc[mt][nt][i] + bi;
      }
    }
}

// ---------------------------------------------------------------------------
extern "C" void kernel_launch(void* const* d_in, const int* in_sizes, int n_in,
                              void* d_out, int out_size, void* d_ws,
                              size_t ws_size, hipStream_t stream) {
  const float* x      = (const float*)d_in[0];
  const float* w_qkv  = (const float*)d_in[1];
  const float* b_qkv  = (const float*)d_in[2];
  const float* w_proj = (const float*)d_in[3];
  const float* b_proj = (const float*)d_in[4];

  float* out     = (float*)d_out;
  float* weights = out + (size_t)MM * CC;

  f16* p      = (f16*)d_ws;
  f16* wqkvT  = p;  p += (size_t)K3C * CC;
  f16* wprojT = p;  p += (size_t)CC * CC;
  f16* x16    = p;  p += (size_t)MMP * CC;
  f16* qb     = p;  p += (size_t)BH * NP * DH;
  f16* kb     = p;  p += (size_t)BH * NP * DH;
  f16* vT     = p;  p += (size_t)BH * DH * NP;
  f16* ctx    = p;  p += (size_t)MMP * CC;

  prep<<<1728 + 576 + 3600 + 192, 256, 0, stream>>>(w_qkv, w_proj, x, wqkvT,
                                                    wprojT, x16, qb, kb, vT);
  qkv_gemm<<<dim3(K3C / 128, MMP / 128), 256, 0, stream>>>(x16, wqkvT, b_qkv,
                                                           qb, kb, vT);
  attn_kernel<<<NWG, 256, 0, stream>>>(qb, kb, vT, weights, ctx);
  proj_gemm<<<dim3(CC / 128, MMP / 128), 256, 0, stream>>>(ctx, wprojT, b_proj,
                                                           out);
}